// Round 8
// baseline (498.208 us; speedup 1.0000x reference)
//
#include <hip/hip_runtime.h>
#include <math.h>
#include <stdint.h>

#define D_MODEL 1024
#define NH      16
#define DK      64
#define BS      4
#define TS      2048
#define M_ROWS  (BS*TS)       // 8192
#define C3      (3*D_MODEL)   // 3072

typedef __attribute__((ext_vector_type(8))) short          short8;
typedef __attribute__((ext_vector_type(4))) float          f32x4;
typedef __attribute__((ext_vector_type(8))) __bf16         bf16x8;
typedef __attribute__((ext_vector_type(4))) unsigned short ushort4_t;

// fp32 -> bf16 round-to-nearest-even
static __device__ __forceinline__ unsigned short f2bf(float f) {
    unsigned u = __builtin_bit_cast(unsigned, f);
    u += 0x7fffu + ((u >> 16) & 1u);
    return (unsigned short)(u >> 16);
}
static __device__ __forceinline__ float bf2f(unsigned short h) {
    unsigned u = ((unsigned)h) << 16;
    return __builtin_bit_cast(float, u);
}
static __device__ __forceinline__ f32x4 mfma16(short8 a, short8 b, f32x4 c) {
    return __builtin_amdgcn_mfma_f32_16x16x32_bf16(
        __builtin_bit_cast(bf16x8, a), __builtin_bit_cast(bf16x8, b), c, 0, 0, 0);
}
// async global->LDS, 16B per lane; LDS dest = wave-uniform base + lane*16
static __device__ __forceinline__ void gll16(const void* g, void* l) {
    __builtin_amdgcn_global_load_lds(
        (const __attribute__((address_space(1))) void*)g,
        (__attribute__((address_space(3))) void*)l, 16, 0, 0);
}

// ---------------------------------------------------------------------------
// cast_split: fp32 -> (bf16 hi, bf16 lo) elementwise. n4 = count/4.
// ---------------------------------------------------------------------------
__global__ __launch_bounds__(256)
void cast_split(const float* __restrict__ src, unsigned short* __restrict__ hi,
                unsigned short* __restrict__ lo, int n4) {
    int i = blockIdx.x * blockDim.x + threadIdx.x;
    const int stride = gridDim.x * blockDim.x;
    for (; i < n4; i += stride) {
        float4 v = reinterpret_cast<const float4*>(src)[i];
        float f0 = v.x, f1 = v.y, f2 = v.z, f3 = v.w;
        ushort4_t h, l;
        h[0] = f2bf(f0); l[0] = f2bf(f0 - bf2f(h[0]));
        h[1] = f2bf(f1); l[1] = f2bf(f1 - bf2f(h[1]));
        h[2] = f2bf(f2); l[2] = f2bf(f2 - bf2f(h[2]));
        h[3] = f2bf(f3); l[3] = f2bf(f3 - bf2f(h[3]));
        reinterpret_cast<ushort4_t*>(hi)[i] = h;
        reinterpret_cast<ushort4_t*>(lo)[i] = l;
    }
}

// ---------------------------------------------------------------------------
// cast_wT: W fp32 [K][N] -> Th, Tl bf16 [N][K] (transposed, k-contiguous).
// ---------------------------------------------------------------------------
__global__ __launch_bounds__(256)
void cast_wT(const float* __restrict__ W, unsigned short* __restrict__ Th,
             unsigned short* __restrict__ Tl, int K, int N) {
    __shared__ float Ls[32][36];
    const int tid = threadIdx.x;
    const int n0 = blockIdx.x * 32, k0 = blockIdx.y * 32;
    {
        const int row = tid >> 3, c4 = tid & 7;
        float4 v = *reinterpret_cast<const float4*>(&W[(size_t)(k0 + row) * N + n0 + c4 * 4]);
        *reinterpret_cast<float4*>(&Ls[row][c4 * 4]) = v;
    }
    __syncthreads();
    {
        const int nl = tid >> 3, c4 = tid & 7;
        ushort4_t h, l;
#pragma unroll
        for (int j = 0; j < 4; ++j) {
            float f = Ls[c4 * 4 + j][nl];
            h[j] = f2bf(f);
            l[j] = f2bf(f - bf2f(h[j]));
        }
        const size_t o = (size_t)(n0 + nl) * K + k0 + c4 * 4;
        *reinterpret_cast<ushort4_t*>(&Th[o]) = h;
        *reinterpret_cast<ushort4_t*>(&Tl[o]) = l;
    }
}

// ---------------------------------------------------------------------------
// gemm_split: C = (Ah+Al)@(Bh+Bl)^T + bias, 3-MFMA split-bf16 (hh, hl, lh).
// ROUND-3 structure verbatim (proven: QKV 176 µs, MfmaUtil 39%, 0 conflicts,
// ~1.7 blocks/CU co-residency hides the barrier drain).
// MODE 0: fp32 out. MODE 1: bf16 hi/lo planes. MODE 2: planes for n<2048,
// V-columns (bn>=2048) written TRANSPOSED to vth/vtl [bh][d][t] — fuses the
// old v_transpose pass into the epilogue (saves a 134 MB r/w pass).
// ---------------------------------------------------------------------------
template <int MODE>
__global__ __launch_bounds__(256)
void gemm_split(const unsigned short* __restrict__ Ah_g, const unsigned short* __restrict__ Al_g,
                const unsigned short* __restrict__ Bh_g, const unsigned short* __restrict__ Bl_g,
                const float* __restrict__ bias,
                float* __restrict__ Cf, unsigned short* __restrict__ Ch,
                unsigned short* __restrict__ Cl,
                unsigned short* __restrict__ vth, unsigned short* __restrict__ vtl,
                int M, int N, int K) {
    __shared__ unsigned short AhL[128 * 32];
    __shared__ unsigned short AlL[128 * 32];
    __shared__ unsigned short BhL[128 * 32];
    __shared__ unsigned short BlL[128 * 32];

    const int tid  = threadIdx.x;
    const int lane = tid & 63, wid = tid >> 6;
    const int wm = wid >> 1, wn = wid & 1;
    const int bm = blockIdx.y * 128, bn = blockIdx.x * 128;
    const int lr = lane & 15, kg = lane >> 4;

    f32x4 acc[4][4];
#pragma unroll
    for (int m = 0; m < 4; ++m)
#pragma unroll
        for (int n = 0; n < 4; ++n) acc[m][n] = (f32x4){0.f, 0.f, 0.f, 0.f};

    for (int k0 = 0; k0 < K; k0 += 32) {
        __syncthreads();               // previous iteration's readers done
#pragma unroll
        for (int j = 0; j < 2; ++j) {
            const int si  = j * 256 + wid * 64 + lane;   // 16B slot 0..511
            const int row = si >> 2, cc = si & 3;
            const int sc  = cc ^ ((row >> 1) & 3);
            const int lo  = (j * 256 + wid * 64) * 8;    // shorts, wave-uniform
            const size_t ga = (size_t)(bm + row) * K + k0 + sc * 8;
            const size_t gb = (size_t)(bn + row) * K + k0 + sc * 8;
            gll16(&Ah_g[ga], &AhL[lo]);
            gll16(&Al_g[ga], &AlL[lo]);
            gll16(&Bh_g[gb], &BhL[lo]);
            gll16(&Bl_g[gb], &BlL[lo]);
        }
        __syncthreads();               // drains vmcnt -> tile visible

        short8 ah[4], al[4], bh[4], bl[4];
#pragma unroll
        for (int m = 0; m < 4; ++m) {
            const int r = wm * 64 + m * 16 + lr;
            const int s = kg ^ ((r >> 1) & 3);
            ah[m] = *reinterpret_cast<const short8*>(&AhL[r * 32 + s * 8]);
            al[m] = *reinterpret_cast<const short8*>(&AlL[r * 32 + s * 8]);
        }
#pragma unroll
        for (int n = 0; n < 4; ++n) {
            const int r = wn * 64 + n * 16 + lr;
            const int s = kg ^ ((r >> 1) & 3);
            bh[n] = *reinterpret_cast<const short8*>(&BhL[r * 32 + s * 8]);
            bl[n] = *reinterpret_cast<const short8*>(&BlL[r * 32 + s * 8]);
        }
#pragma unroll
        for (int m = 0; m < 4; ++m)
#pragma unroll
            for (int n = 0; n < 4; ++n) {
                acc[m][n] = mfma16(ah[m], bh[n], acc[m][n]);
                acc[m][n] = mfma16(ah[m], bl[n], acc[m][n]);
                acc[m][n] = mfma16(al[m], bh[n], acc[m][n]);
            }
    }

    const int og = lane >> 4, oc = lane & 15;
    if (MODE == 2 && bn >= 2048) {
        // ---- fused V-transpose epilogue: vt[bh][d][t] hi/lo planes --------
#pragma unroll
        for (int n = 0; n < 4; ++n) {
            const int gc = bn + wn * 64 + n * 16 + oc;
            const float bz = bias[gc];
            const int vb  = gc - 2048;
            const int hh_ = vb >> 6, dd = vb & 63;
#pragma unroll
            for (int m = 0; m < 4; ++m) {
                const int gr0 = bm + wm * 64 + m * 16 + og * 4;
                ushort4_t vh4, vl4;
#pragma unroll
                for (int rr = 0; rr < 4; ++rr) {
                    const float v = acc[m][n][rr] + bz;
                    vh4[rr] = f2bf(v);
                    vl4[rr] = f2bf(v - bf2f(vh4[rr]));
                }
                const size_t o = ((size_t)((gr0 >> 11) * 16 + hh_) * 64 + dd) * 2048
                               + (size_t)(gr0 & 2047);
                *reinterpret_cast<ushort4_t*>(&vth[o]) = vh4;
                *reinterpret_cast<ushort4_t*>(&vtl[o]) = vl4;
            }
        }
    } else {
#pragma unroll
        for (int n = 0; n < 4; ++n) {
            const int gc = bn + wn * 64 + n * 16 + oc;
            const float bz = bias[gc];
#pragma unroll
            for (int m = 0; m < 4; ++m) {
                const int gr0 = bm + wm * 64 + m * 16 + og * 4;
#pragma unroll
                for (int rr = 0; rr < 4; ++rr) {
                    const float v = acc[m][n][rr] + bz;
                    const size_t idx = (size_t)(gr0 + rr) * N + gc;
                    if (MODE >= 1) {
                        const unsigned short hh = f2bf(v);
                        Ch[idx] = hh;
                        Cl[idx] = f2bf(v - bf2f(hh));
                    } else {
                        Cf[idx] = v;
                    }
                }
            }
        }
    }
}

// ---------------------------------------------------------------------------
// attn_mfma: causal flash attention (round-4 inner mechanics, new grid).
// ROUND 7: grid (8, 64) — one q-tile (256 rows) per block, 8 waves x 32 rows.
// LDS 80 KB -> 2 blocks/CU co-resident; cross-block overlap fills the
// per-iter barrier/drain stalls (the round-3-GEMM lesson). nkt = 4*qt+4 is
// imbalanced per block but averages at 2 blocks/CU.
// K/V LDS-staged double-buffered via swizzled-source global_load_lds;
// swapped-operand QK^T (q lane-local -> 2-shfl softmax); setprio on MFMA.
// ---------------------------------------------------------------------------
__global__ __launch_bounds__(512, 2)
void attn_mfma(const unsigned short* __restrict__ qkvh,
               const unsigned short* __restrict__ vth, const unsigned short* __restrict__ vtl,
               unsigned short* __restrict__ yh, unsigned short* __restrict__ yl) {
    const int qt = blockIdx.x;                 // q-tile 0..7
    const int bh = blockIdx.y;                 // 0..63
    const int b = bh >> 4, h = bh & 15;
    const int tid = threadIdx.x, w = tid >> 6, lane = tid & 63;
    const int lr = lane & 15, lg = lane >> 4;

    __shared__ unsigned short Kt[2][64 * 64];
    __shared__ unsigned short Vhs[2][64 * 64];
    __shared__ unsigned short Vls[2][64 * 64];
    __shared__ unsigned short Ps[8][32 * 64];

    const size_t kbase  = (size_t)b * TS * C3 + D_MODEL + (size_t)h * DK;
    const size_t vbase  = (size_t)bh * DK * TS;
    const size_t qbase  = (size_t)b * TS * C3 + (size_t)h * DK;
    unsigned short* PsW = &Ps[w][0];

    const f32x4 fz = (f32x4){0.f, 0.f, 0.f, 0.f};

    const int srow = tid >> 3;
    const int ssc  = (tid & 7) ^ (srow & 7);
    const int slds = (w * 64) * 8;

    const int qwbase = qt * 256 + w * 32;      // wave's first q-row

    short8 qreg[2][2];
#pragma unroll
    for (int mf = 0; mf < 2; ++mf) {
        const size_t qrow = qbase + (size_t)(qwbase + mf * 16 + lr) * C3;
        qreg[mf][0] = *reinterpret_cast<const short8*>(&qkvh[qrow + lg * 8]);
        qreg[mf][1] = *reinterpret_cast<const short8*>(&qkvh[qrow + 32 + lg * 8]);
    }

    f32x4 yacc[4][2];
#pragma unroll
    for (int df = 0; df < 4; ++df)
#pragma unroll
        for (int qf = 0; qf < 2; ++qf) yacc[df][qf] = fz;
    float mrun[2], lrun[2];
#pragma unroll
    for (int qf = 0; qf < 2; ++qf) { mrun[qf] = -1e30f; lrun[qf] = 0.f; }

    const int nkt = 4 * qt + 4;
    int cur = 0;

    auto stage = [&](int buf, int kt) {
        gll16(&qkvh[kbase + (size_t)(kt * 64 + srow) * C3 + ssc * 8], &Kt[buf][slds]);
        gll16(&vth[vbase + (size_t)srow * TS + kt * 64 + ssc * 8], &Vhs[buf][slds]);
        gll16(&vtl[vbase + (size_t)srow * TS + kt * 64 + ssc * 8], &Vls[buf][slds]);
    };
    auto ldsf = [&](const unsigned short* Tt, int row, int kslot) -> short8 {
        return *reinterpret_cast<const short8*>(
            reinterpret_cast<const char*>(Tt) + row * 128 + (((kslot ^ (row & 7)) & 7) << 4));
    };

    stage(cur, 0);
    for (int kt = 0; kt < nkt; ++kt) {
        __syncthreads();                   // tile kt ready; prev readers done
        if (kt + 1 < nkt) stage(cur ^ 1, kt + 1);

        if (kt * 64 <= qwbase + 31) {      // wave-uniform: skip fully-masked tiles
            f32x4 s[2][4];
            __builtin_amdgcn_s_setprio(1);
#pragma unroll
            for (int nf = 0; nf < 4; ++nf) {
                const int krow = nf * 16 + lr;
                short8 ka0 = ldsf(Kt[cur], krow, lg);
                short8 ka1 = ldsf(Kt[cur], krow, 4 + lg);
#pragma unroll
                for (int mf = 0; mf < 2; ++mf)
                    s[mf][nf] = mfma16(ka1, qreg[mf][1], mfma16(ka0, qreg[mf][0], fz));
            }
            __builtin_amdgcn_s_setprio(0);
#pragma unroll
            for (int mf = 0; mf < 2; ++mf)
#pragma unroll
                for (int nf = 0; nf < 4; ++nf) s[mf][nf] *= 0.125f;
            if (kt * 64 + 63 > qwbase) {
#pragma unroll
                for (int mf = 0; mf < 2; ++mf) {
                    const int q = qwbase + mf * 16 + lr;
#pragma unroll
                    for (int nf = 0; nf < 4; ++nf)
#pragma unroll
                        for (int rr = 0; rr < 4; ++rr)
                            if (kt * 64 + nf * 16 + lg * 4 + rr > q) s[mf][nf][rr] = -1e30f;
                }
            }
            float sclv[2];
#pragma unroll
            for (int mf = 0; mf < 2; ++mf) {
                float rm = s[mf][0][0];
#pragma unroll
                for (int nf = 0; nf < 4; ++nf)
#pragma unroll
                    for (int rr = 0; rr < 4; ++rr) rm = fmaxf(rm, s[mf][nf][rr]);
                rm = fmaxf(rm, __shfl_xor(rm, 16, 64));
                rm = fmaxf(rm, __shfl_xor(rm, 32, 64));
                const float mn = fmaxf(mrun[mf], rm);
                float rs = 0.f;
#pragma unroll
                for (int nf = 0; nf < 4; ++nf)
#pragma unroll
                    for (int rr = 0; rr < 4; ++rr) {
                        const float p = __expf(s[mf][nf][rr] - mn);
                        s[mf][nf][rr] = p;
                        rs += p;
                    }
                rs += __shfl_xor(rs, 16, 64);
                rs += __shfl_xor(rs, 32, 64);
                sclv[mf] = __expf(mrun[mf] - mn);
                lrun[mf] = lrun[mf] * sclv[mf] + rs;
                mrun[mf] = mn;
            }
#pragma unroll
            for (int df = 0; df < 4; ++df)
#pragma unroll
                for (int qf = 0; qf < 2; ++qf) yacc[df][qf] *= sclv[qf];
#pragma unroll
            for (int mf = 0; mf < 2; ++mf) {
                const int q = mf * 16 + lr;
#pragma unroll
                for (int nf = 0; nf < 4; ++nf) {
                    ushort4_t pw;
                    pw[0] = f2bf(s[mf][nf][0]);
                    pw[1] = f2bf(s[mf][nf][1]);
                    pw[2] = f2bf(s[mf][nf][2]);
                    pw[3] = f2bf(s[mf][nf][3]);
                    *reinterpret_cast<ushort4_t*>(
                        reinterpret_cast<char*>(PsW) +
                        ((q * 128 + (nf * 16 + lg * 4) * 2) ^ ((q & 7) << 4))) = pw;
                }
            }
#pragma unroll
            for (int kf = 0; kf < 2; ++kf) {
                short8 pb[2];
#pragma unroll
                for (int qf = 0; qf < 2; ++qf) {
                    const int q = qf * 16 + lr;
                    pb[qf] = *reinterpret_cast<const short8*>(
                        reinterpret_cast<const char*>(PsW) +
                        q * 128 + ((((kf << 2) + lg) ^ (q & 7)) << 4));
                }
                __builtin_amdgcn_s_setprio(1);
#pragma unroll
                for (int df = 0; df < 4; ++df) {
                    const int d = df * 16 + lr;
                    short8 va = ldsf(Vhs[cur], d, (kf << 2) + lg);
                    short8 vb = ldsf(Vls[cur], d, (kf << 2) + lg);
#pragma unroll
                    for (int qf = 0; qf < 2; ++qf) {
                        yacc[df][qf] = mfma16(va, pb[qf], yacc[df][qf]);
                        yacc[df][qf] = mfma16(vb, pb[qf], yacc[df][qf]);
                    }
                }
                __builtin_amdgcn_s_setprio(0);
            }
        }
        cur ^= 1;
    }

#pragma unroll
    for (int qf = 0; qf < 2; ++qf) {
        const float inv = 1.f / lrun[qf];
        const size_t ro = ((size_t)b * TS + (qwbase + qf * 16 + lr)) * D_MODEL + h * DK;
#pragma unroll
        for (int df = 0; df < 4; ++df) {
            ushort4_t oh, ol;
#pragma unroll
            for (int rr = 0; rr < 4; ++rr) {
                const float v = yacc[df][qf][rr] * inv;
                oh[rr] = f2bf(v);
                ol[rr] = f2bf(v - bf2f(oh[rr]));
            }
            *reinterpret_cast<ushort4_t*>(&yh[ro + df * 16 + lg * 4]) = oh;
            *reinterpret_cast<ushort4_t*>(&yl[ro + df * 16 + lg * 4]) = ol;
        }
    }
}

// ---------------------------------------------------------------------------
extern "C" void kernel_launch(void* const* d_in, const int* in_sizes, int n_in,
                              void* d_out, int out_size, void* d_ws, size_t ws_size,
                              hipStream_t stream) {
    const float* x      = (const float*)d_in[0];
    const float* W_qkv  = (const float*)d_in[1];
    const float* b_qkv  = (const float*)d_in[2];
    const float* W_proj = (const float*)d_in[3];
    const float* b_proj = (const float*)d_in[4];
    float* out = (float*)d_out;

    char* ws = (char*)d_ws;
    size_t off = 0;
    auto carve = [&](size_t elems) {
        unsigned short* p = (unsigned short*)(ws + off);
        off += elems * sizeof(unsigned short);
        return p;
    };
    unsigned short* xh   = carve((size_t)M_ROWS * D_MODEL);
    unsigned short* xl   = carve((size_t)M_ROWS * D_MODEL);
    unsigned short* wqh  = carve((size_t)C3 * D_MODEL);
    unsigned short* wql  = carve((size_t)C3 * D_MODEL);
    unsigned short* wph  = carve((size_t)D_MODEL * D_MODEL);
    unsigned short* wpl  = carve((size_t)D_MODEL * D_MODEL);
    unsigned short* qkvh = carve((size_t)M_ROWS * C3);
    unsigned short* qkvl = carve((size_t)M_ROWS * C3);
    unsigned short* vth  = carve((size_t)BS * NH * DK * TS);
    unsigned short* vtl  = carve((size_t)BS * NH * DK * TS);
    unsigned short* yhh  = carve((size_t)M_ROWS * D_MODEL);
    unsigned short* yll  = carve((size_t)M_ROWS * D_MODEL);

    cast_split<<<2048, 256, 0, stream>>>(x, xh, xl, M_ROWS * D_MODEL / 4);
    cast_wT<<<dim3(C3 / 32, D_MODEL / 32), 256, 0, stream>>>(W_qkv, wqh, wql, D_MODEL, C3);
    cast_wT<<<dim3(D_MODEL / 32, D_MODEL / 32), 256, 0, stream>>>(W_proj, wph, wpl, D_MODEL, D_MODEL);

    // qkv = x @ W_qkv + b_qkv; V-third written transposed to vth/vtl (fused)
    gemm_split<2><<<dim3(C3 / 128, M_ROWS / 128), 256, 0, stream>>>(
        xh, xl, wqh, wql, b_qkv, nullptr, qkvh, qkvl, vth, vtl, M_ROWS, C3, D_MODEL);

    // causal flash attention; one q-tile per block -> 2 blocks/CU
    attn_mfma<<<dim3(8, BS * NH), 512, 0, stream>>>(qkvh, vth, vtl, yhh, yll);

    // out = y @ W_proj + b_proj
    gemm_split<0><<<dim3(D_MODEL / 128, M_ROWS / 128), 256, 0, stream>>>(
        yhh, yll, wph, wpl, b_proj, out, nullptr, nullptr, nullptr, nullptr,
        M_ROWS, D_MODEL, D_MODEL);
}